// Round 13
// baseline (20200.153 us; speedup 1.0000x reference)
//
#include <hip/hip_runtime.h>
#include <hip/hip_bf16.h>

// Problem constants
#define B    16
#define TIN  400
#define TT   100
#define EMBD 128
#define VV   32000
#define NV   31998
#define NVB  224      // vocab blocks
#define NB   256      // decoder blocks
#define LR   112      // Wv2 rows in LDS per vocab block
// roles: CELL 0-15 (batch b) | ATTN+FC1 16-31 (b) | VOCAB 32-255 (255 also FINAL)
// tokens: UNK=0, START=1, END=2, PAD=3

typedef unsigned uint4v __attribute__((ext_vector_type(4)));

__device__ __forceinline__ float sigf(float x) { return 1.f / (1.f + __expf(-x)); }
__device__ __forceinline__ float fast_tanh(float x) {
    float e = __expf(2.f * x);
    return 1.f - 2.f / (e + 1.f);
}
__device__ __forceinline__ float bflo(unsigned u) { return __uint_as_float(u << 16); }
__device__ __forceinline__ float bfhi(unsigned u) { return __uint_as_float(u & 0xffff0000u); }
__device__ __forceinline__ unsigned short f2bf(float f) {
    unsigned u = __float_as_uint(f);
    return (unsigned short)((u + 0x7fffu + ((u >> 16) & 1u)) >> 16);
}
__device__ __forceinline__ unsigned packbf(float a, float b) {
    return (unsigned)f2bf(a) | ((unsigned)f2bf(b) << 16);
}
// uncached coherence-point ops (relaxed agent atomics) — proven R7-R12
__device__ __forceinline__ float cldf(const float* p) {
    return __hip_atomic_load(p, __ATOMIC_RELAXED, __HIP_MEMORY_SCOPE_AGENT);
}
__device__ __forceinline__ unsigned cldu(const unsigned* p) {
    return __hip_atomic_load(p, __ATOMIC_RELAXED, __HIP_MEMORY_SCOPE_AGENT);
}
__device__ __forceinline__ unsigned long long cldu2(const unsigned long long* p) {
    return __hip_atomic_load(p, __ATOMIC_RELAXED, __HIP_MEMORY_SCOPE_AGENT);
}
__device__ __forceinline__ void stf(float* p, float v) {
    __hip_atomic_store(p, v, __ATOMIC_RELAXED, __HIP_MEMORY_SCOPE_AGENT);
}
__device__ __forceinline__ void stu(unsigned* p, unsigned v) {
    __hip_atomic_store(p, v, __ATOMIC_RELAXED, __HIP_MEMORY_SCOPE_AGENT);
}

// ---- epoch sync ----
template<int SLP>
__device__ __forceinline__ void wait_np(int* arr, int n, int ep, int tid) {
    for (int i = tid; i < n; i += 256) {
        while (__hip_atomic_load(&arr[i * 16], __ATOMIC_RELAXED, __HIP_MEMORY_SCOPE_AGENT) < ep)
            __builtin_amdgcn_s_sleep(SLP);
    }
    __syncthreads();
    asm volatile("" ::: "memory");
}
template<int SLP>
__device__ __forceinline__ void wait_line(int* l, int ep) {
    if (threadIdx.x == 0) {
        while (__hip_atomic_load(l, __ATOMIC_RELAXED, __HIP_MEMORY_SCOPE_AGENT) < ep)
            __builtin_amdgcn_s_sleep(SLP);
    }
    __syncthreads();
    asm volatile("" ::: "memory");
}
__device__ __forceinline__ void arrive(int* arr, int idx, int ep) {
    __syncthreads();
    if (threadIdx.x == 0)
        __hip_atomic_store(&arr[idx * 16], ep, __ATOMIC_RELEASE, __HIP_MEMORY_SCOPE_AGENT);
}

// ---------------------------------------------------------------- zero
__global__ __launch_bounds__(256) void k_zero(float* __restrict__ p, int n) {
    int i = blockIdx.x * 256 + threadIdx.x;
    if (i < n) p[i] = 0.f;
}

// ---------------------------------------------------------------- fp32 -> bf16 (RNE)
__global__ __launch_bounds__(256) void k_cvt(const float* __restrict__ src, unsigned short* __restrict__ dst, int n) {
    int i = blockIdx.x * 256 + threadIdx.x;
    if (i < n) dst[i] = f2bf(src[i]);
}

// ---------------------------------------------------------------- pack [A|B] rows -> bf16
__global__ __launch_bounds__(256) void k_pack(const float* __restrict__ A, int wA,
                                              const float* __restrict__ Bw, int wB,
                                              unsigned short* __restrict__ dst, int rows) {
    int i = blockIdx.x * 256 + threadIdx.x;
    int W = wA + wB;
    if (i < rows * W) {
        int r = i / W, k = i - r * W;
        float v = (k < wA) ? A[(size_t)r * wA + k] : Bw[(size_t)r * wB + (k - wA)];
        dst[i] = f2bf(v);
    }
}

// ------------------------------------------------ encoder input GEMM L0 (proven)
__global__ __launch_bounds__(256) void k_gx0(const int* __restrict__ ids, const float* __restrict__ emb,
                                             const float* __restrict__ Wih, const float* __restrict__ bias,
                                             float* __restrict__ gx) {
    int blk = blockIdx.x, dir = blk / TIN, t = blk % TIN;
    __shared__ float se[16][132];
    int tid = threadIdx.x;
    for (int i = tid; i < 16 * 128; i += 256) {
        int b = i >> 7, k = i & 127;
        int id = ids[b * TIN + t];
        if ((unsigned)id >= VV) id = 0;
        se[b][k] = emb[(size_t)id * EMBD + k];
    }
    __syncthreads();
    const float* W = Wih + (size_t)dir * 1024 * EMBD;
    const float* bb = bias + (size_t)dir * 1024;
    float* out = gx + ((size_t)dir * TIN + t) * (B * 1024);
    for (int c = tid; c < 1024; c += 256) {
        float acc[16];
#pragma unroll
        for (int b = 0; b < 16; b++) acc[b] = 0.f;
        const float4* wr = (const float4*)(W + (size_t)c * EMBD);
        for (int k4 = 0; k4 < 32; k4++) {
            float4 w = wr[k4];
            int k = k4 * 4;
#pragma unroll
            for (int b = 0; b < 16; b++)
                acc[b] += w.x * se[b][k] + w.y * se[b][k + 1] + w.z * se[b][k + 2] + w.w * se[b][k + 3];
        }
        float bv = bb[c];
#pragma unroll
        for (int b = 0; b < 16; b++) out[(size_t)b * 1024 + c] = acc[b] + bv;
    }
}

// ------------------------------------------------ encoder input GEMM L1 (proven)
__global__ __launch_bounds__(256) void k_gx1(const float* __restrict__ hseq, const float* __restrict__ Wih,
                                             const float* __restrict__ bias, float* __restrict__ gx) {
    int blk = blockIdx.x, dir = blk / TIN, t = blk % TIN;
    __shared__ float sx[16][516];
    int tid = threadIdx.x;
    for (int i = tid; i < 16 * 512; i += 256) sx[i >> 9][i & 511] = hseq[(size_t)t * B * 512 + i];
    __syncthreads();
    const float* W = Wih + (size_t)dir * 1024 * 512;
    const float* bb = bias + (size_t)dir * 1024;
    float* out = gx + ((size_t)dir * TIN + t) * (B * 1024);
    for (int c = tid; c < 1024; c += 256) {
        float acc[16];
#pragma unroll
        for (int b = 0; b < 16; b++) acc[b] = 0.f;
        const float4* wr = (const float4*)(W + (size_t)c * 512);
        for (int k4 = 0; k4 < 128; k4++) {
            float4 w = wr[k4];
            int k = k4 * 4;
#pragma unroll
            for (int b = 0; b < 16; b++)
                acc[b] += w.x * sx[b][k] + w.y * sx[b][k + 1] + w.z * sx[b][k + 2] + w.w * sx[b][k + 3];
        }
        float bv = bb[c];
#pragma unroll
        for (int b = 0; b < 16; b++) out[(size_t)b * 1024 + c] = acc[b] + bv;
    }
}

// ------------------------------------------------ persistent encoder layer (proven R12)
__device__ __forceinline__ void slot_signal_e(int* sl, int idx) {
    __syncthreads();
    if (threadIdx.x == 0)
        __hip_atomic_store(&sl[idx * 16], 1, __ATOMIC_RELEASE, __HIP_MEMORY_SCOPE_AGENT);
}
__device__ __forceinline__ void slot_wait_e(int* sl, int n, int tid) {
    for (int i = tid; i < n; i += 256) {
        while (__hip_atomic_load(&sl[i * 16], __ATOMIC_RELAXED, __HIP_MEMORY_SCOPE_AGENT) == 0)
            __builtin_amdgcn_s_sleep(2);
    }
    __syncthreads();
    asm volatile("" ::: "memory");
}
__global__ __launch_bounds__(256) void k_enc_layer(const float* __restrict__ gx, const float* __restrict__ Whh,
                                                   float* __restrict__ hbuf, float* __restrict__ hout,
                                                   float* __restrict__ hTs, float* __restrict__ cTs,
                                                   int* __restrict__ slots, int layer) {
    int blk = blockIdx.x;
    int dir = blk >> 4;
    int ublk = blk & 15;
    int tid = threadIdx.x;
    int rp = tid >> 3, q = tid & 7;
    int lr0 = rp * 2, lr1 = lr0 + 1;
    int g0 = lr0 & 3, g1 = lr1 & 3;
    int unit0 = ublk * 16 + (lr0 >> 2);
    int unit1 = ublk * 16 + (lr1 >> 2);
    const float* Wd = Whh + (size_t)dir * 1024 * 256;
    float wreg[64];
    {
        const float* r0 = Wd + (size_t)(g0 * 256 + unit0) * 256 + q * 32;
        const float* r1 = Wd + (size_t)(g1 * 256 + unit1) * 256 + q * 32;
#pragma unroll
        for (int e = 0; e < 32; e++) { wreg[e] = r0[e]; wreg[32 + e] = r1[e]; }
    }
    int ub = tid >> 4, bb = tid & 15;
    float creg = 0.f;
    __shared__ float sh[16 * 288];
    __shared__ float sums[32 * 17];
    __shared__ float sums2[32 * 17];
    int* dirslots = slots + (size_t)dir * TIN * 16 * 16;

    for (int s = 0; s < TIN; s++) {
        int t = dir ? (TIN - 1 - s) : s;
        int par = s & 1;
        {
            const unsigned long long* hp = (const unsigned long long*)(hbuf + ((size_t)par * 2 + dir) * B * 256);
            unsigned long long v[8];
#pragma unroll
            for (int j = 0; j < 8; j++) v[j] = cldu2(hp + tid + 256 * j);
#pragma unroll
            for (int j = 0; j < 8; j++) {
                int k2 = (tid + 256 * j) * 2;
                int b = k2 >> 8, k = k2 & 255;
                float* d = &sh[b * 288 + (k >> 5) * 36 + (k & 31)];
                d[0] = __uint_as_float((unsigned)v[j]);
                d[1] = __uint_as_float((unsigned)(v[j] >> 32));
            }
        }
        __syncthreads();
        float pa0[16], pa1[16];
        for (int b = 0; b < 16; b++) {
            const float4* hv = (const float4*)&sh[b * 288 + q * 36];
            float a0 = 0.f, a1 = 0.f;
#pragma unroll
            for (int j = 0; j < 8; j++) {
                float4 h4 = hv[j];
                a0 += wreg[4 * j] * h4.x + wreg[4 * j + 1] * h4.y + wreg[4 * j + 2] * h4.z + wreg[4 * j + 3] * h4.w;
                a1 += wreg[32 + 4 * j] * h4.x + wreg[33 + 4 * j] * h4.y + wreg[34 + 4 * j] * h4.z + wreg[35 + 4 * j] * h4.w;
            }
            pa0[b] = a0; pa1[b] = a1;
        }
#pragma unroll
        for (int m = 1; m < 8; m <<= 1) {
#pragma unroll
            for (int b = 0; b < 16; b++) {
                pa0[b] += __shfl_xor(pa0[b], m, 64);
                pa1[b] += __shfl_xor(pa1[b], m, 64);
            }
        }
        if (q == 0) {
            float* s0 = (lr0 < 32) ? sums : sums2;
            float* s1 = (lr1 < 32) ? sums : sums2;
            int l0 = lr0 & 31, l1 = lr1 & 31;
#pragma unroll
            for (int b = 0; b < 16; b++) { s0[l0 * 17 + b] = pa0[b]; s1[l1 * 17 + b] = pa1[b]; }
        }
        __syncthreads();
        {
            int unit = ublk * 16 + ub;
            const float* gp = gx + (((size_t)dir * TIN + t) * B + bb) * 1024;
            int lri = ub * 4;
            float ai = ((lri + 0 < 32) ? sums[(lri + 0) * 17 + bb] : sums2[((lri + 0) & 31) * 17 + bb]) + gp[0 * 256 + unit];
            float af = ((lri + 1 < 32) ? sums[(lri + 1) * 17 + bb] : sums2[((lri + 1) & 31) * 17 + bb]) + gp[1 * 256 + unit];
            float ag = ((lri + 2 < 32) ? sums[(lri + 2) * 17 + bb] : sums2[((lri + 2) & 31) * 17 + bb]) + gp[2 * 256 + unit];
            float ao = ((lri + 3 < 32) ? sums[(lri + 3) * 17 + bb] : sums2[((lri + 3) & 31) * 17 + bb]) + gp[3 * 256 + unit];
            float c = sigf(af) * creg + sigf(ai) * fast_tanh(ag);
            float h = sigf(ao) * fast_tanh(c);
            creg = c;
            stf(&hbuf[((size_t)(par ^ 1) * 2 + dir) * B * 256 + (size_t)bb * 256 + unit], h);
            if (layer == 0) hout[((size_t)t * B + bb) * 512 + dir * 256 + unit] = h;
            else            hout[((size_t)bb * TIN + t) * 512 + dir * 256 + unit] = h;
            if (s == TIN - 1) {
                hTs[((size_t)layer * B + bb) * 512 + dir * 256 + unit] = h;
                cTs[((size_t)layer * B + bb) * 512 + dir * 256 + unit] = c;
            }
        }
        int* sl = dirslots + (size_t)s * 16 * 16;
        slot_signal_e(sl, ublk);
        slot_wait_e(sl, 16, tid);
    }
}

// ------------------------------------------------ enc_attn precompute (proven)
__global__ __launch_bounds__(256) void k_encattn(const float* __restrict__ encs, const float* __restrict__ Wea,
                                                 const float* __restrict__ bea, unsigned short* __restrict__ encat) {
    int blk = blockIdx.x;
    __shared__ float sx[8][520];
    int tid = threadIdx.x;
    for (int i = tid; i < 8 * 512; i += 256) {
        int r = i >> 9, k = i & 511;
        sx[r][k] = encs[((size_t)blk * 8 + r) * 512 + k];
    }
    __syncthreads();
    float a[8];
    float bv = bea[tid];
#pragma unroll
    for (int r = 0; r < 8; r++) a[r] = bv;
    const float4* wr = (const float4*)(Wea + (size_t)tid * 512);
    for (int k4 = 0; k4 < 128; k4++) {
        float4 w = wr[k4];
        int k = k4 * 4;
#pragma unroll
        for (int r = 0; r < 8; r++)
            a[r] += w.x * sx[r][k] + w.y * sx[r][k + 1] + w.z * sx[r][k + 2] + w.w * sx[r][k + 3];
    }
#pragma unroll
    for (int r = 0; r < 8; r++)
        encat[((size_t)blk * 8 + r) * 256 + tid] = f2bf(a[r]);
}

// ------------------------------------------------ decoder init (proven)
__global__ __launch_bounds__(256) void k_dec_init(const float* __restrict__ hTs, const float* __restrict__ cTs,
                                                  const float* __restrict__ Wh, const float* __restrict__ bh,
                                                  const float* __restrict__ Wc, const float* __restrict__ bc,
                                                  float* __restrict__ h0s, float* __restrict__ c0,
                                                  float* __restrict__ h1s, float* __restrict__ c1) {
    int idx = blockIdx.x * 256 + threadIdx.x;
    int l = idx >> 12, b = (idx >> 8) & 15, d = idx & 255;
    const float4* h4 = (const float4*)(hTs + ((size_t)l * B + b) * 512);
    const float4* c4 = (const float4*)(cTs + ((size_t)l * B + b) * 512);
    const float4* wh4 = (const float4*)(Wh + (size_t)d * 512);
    const float4* wc4 = (const float4*)(Wc + (size_t)d * 512);
    float ah = bh[d], ac = bc[d];
    for (int k4 = 0; k4 < 128; k4++) {
        float4 w = wh4[k4], x = h4[k4];
        ah += w.x * x.x + w.y * x.y + w.z * x.z + w.w * x.w;
        w = wc4[k4]; x = c4[k4];
        ac += w.x * x.x + w.y * x.y + w.z * x.z + w.w * x.w;
    }
    if (l == 0) { h0s[(size_t)b * 256 + d] = ah; c0[(size_t)b * 256 + d] = ac; }
    else        { h1s[(size_t)b * 256 + d] = ah; c1[(size_t)b * 256 + d] = ac; }
}

// ------------------------------------------------ persistent decoder (batch-split cells + relay)
__global__ __launch_bounds__(256, 1) void k_dec_persist(
    const int* __restrict__ ids, const int* __restrict__ tgt, const int* __restrict__ tlen,
    const float* __restrict__ emb,
    const unsigned short* __restrict__ CW0B, const float* __restrict__ db0,
    const unsigned short* __restrict__ CW1B, const float* __restrict__ db1,
    const float* __restrict__ Wda, const float* __restrict__ wcov, const float* __restrict__ vat,
    const unsigned short* __restrict__ WV1B, const float* __restrict__ bv1,
    const unsigned short* __restrict__ W2b, const float* __restrict__ bv2,
    const float* __restrict__ wctx, const float* __restrict__ bctx,
    const float* __restrict__ wdec, const float* __restrict__ wemb,
    const unsigned short* __restrict__ ENCATH, const unsigned short* __restrict__ ENCSH,
    float* __restrict__ COVL,
    unsigned* __restrict__ H1B, unsigned* __restrict__ CTXB,
    unsigned* __restrict__ FC1B, unsigned* __restrict__ RELAY,
    float* __restrict__ PCOPYR, float* __restrict__ VPARTR, float* __restrict__ LTGTR,
    const float* __restrict__ H0I, const float* __restrict__ C0i,
    const float* __restrict__ H1I, const float* __restrict__ C1i,
    int* __restrict__ SL, float* __restrict__ out)
{
    __shared__ float smem[39040];
    int blk = blockIdx.x, tid = threadIdx.x;
    int* CELLRDY = SL;               // 16
    int* ATTNRDY = SL + 16 * 16;     // 16
    int* SVOC    = SL + 32 * 16;     // 224
    int* RELAYRDY= SL + 256 * 16;    // 8
    int* FINRDY  = SL + 264 * 16;    // 1
    int* CLAIM   = SL + 272 * 16;    // 8

    if (blk < 16) {
        // ================================================= CELL (batch b, sync-free recurrence)
        int b = blk, u = tid;
        float* xemb = smem;          // 128
        float* h0 = smem + 128;      // 256
        float* h1 = smem + 384;      // 256
        float c0reg = C0i[b * 256 + u];
        float c1reg = C1i[b * 256 + u];
        h0[u] = H0I[b * 256 + u];
        h1[u] = H1I[b * 256 + u];
        __syncthreads();
        for (int t = 0; t < TT; t++) {
            int p16 = t & 15;
            wait_line<8>(FINRDY, t - 15);
            int tok = (t == 0) ? 1 : tgt[b * TT + t - 1];
            if ((unsigned)tok >= VV) tok = 0;
            if (tid < 128) xemb[tid] = emb[(size_t)tok * 128 + tid];
            __syncthreads();
            // ---- cell0: rows g*256+u over K=384 = [emb|h0]
            float acc0[4];
#pragma unroll
            for (int g = 0; g < 4; g++) {
                const uint4* wr = (const uint4*)CW0B + (size_t)(g * 256 + u) * 48;
                float a = 0.f;
                for (int i = 0; i < 16; i++) {
                    uint4 q = wr[i]; int k = i * 8;
                    a += bflo(q.x) * xemb[k]     + bfhi(q.x) * xemb[k + 1]
                       + bflo(q.y) * xemb[k + 2] + bfhi(q.y) * xemb[k + 3]
                       + bflo(q.z) * xemb[k + 4] + bfhi(q.z) * xemb[k + 5]
                       + bflo(q.w) * xemb[k + 6] + bfhi(q.w) * xemb[k + 7];
                }
                for (int i = 16; i < 48; i++) {
                    uint4 q = wr[i]; int k = i * 8 - 128;
                    a += bflo(q.x) * h0[k]     + bfhi(q.x) * h0[k + 1]
                       + bflo(q.y) * h0[k + 2] + bfhi(q.y) * h0[k + 3]
                       + bflo(q.z) * h0[k + 4] + bfhi(q.z) * h0[k + 5]
                       + bflo(q.w) * h0[k + 6] + bfhi(q.w) * h0[k + 7];
                }
                acc0[g] = a;
            }
            {
                float ai = acc0[0] + db0[u], af = acc0[1] + db0[256 + u];
                float ag = acc0[2] + db0[512 + u], ao = acc0[3] + db0[768 + u];
                float c = sigf(af) * c0reg + sigf(ai) * fast_tanh(ag);
                float h = sigf(ao) * fast_tanh(c);
                c0reg = c;
                __syncthreads();
                h0[u] = h;
            }
            __syncthreads();
            // ---- cell1: rows over K=512 = [h0|h1]
            float acc1[4];
#pragma unroll
            for (int g = 0; g < 4; g++) {
                const uint4* wr = (const uint4*)CW1B + (size_t)(g * 256 + u) * 64;
                float a = 0.f;
                for (int i = 0; i < 32; i++) {
                    uint4 q = wr[i]; int k = i * 8;
                    a += bflo(q.x) * h0[k]     + bfhi(q.x) * h0[k + 1]
                       + bflo(q.y) * h0[k + 2] + bfhi(q.y) * h0[k + 3]
                       + bflo(q.z) * h0[k + 4] + bfhi(q.z) * h0[k + 5]
                       + bflo(q.w) * h0[k + 6] + bfhi(q.w) * h0[k + 7];
                }
                for (int i = 32; i < 64; i++) {
                    uint4 q = wr[i]; int k = i * 8 - 256;
                    a += bflo(q.x) * h1[k]     + bfhi(q.x) * h1[k + 1]
                       + bflo(q.y) * h1[k + 2] + bfhi(q.y) * h1[k + 3]
                       + bflo(q.z) * h1[k + 4] + bfhi(q.z) * h1[k + 5]
                       + bflo(q.w) * h1[k + 6] + bfhi(q.w) * h1[k + 7];
                }
                acc1[g] = a;
            }
            {
                float ai = acc1[0] + db1[u], af = acc1[1] + db1[256 + u];
                float ag = acc1[2] + db1[512 + u], ao = acc1[3] + db1[768 + u];
                float c = sigf(af) * c1reg + sigf(ai) * fast_tanh(ag);
                float h = sigf(ao) * fast_tanh(c);
                c1reg = c;
                __syncthreads();
                h1[u] = h;
            }
            __syncthreads();
            if (tid < 128)
                stu(&H1B[p16 * 2048 + b * 128 + tid], packbf(h1[2 * tid], h1[2 * tid + 1]));
            arrive(CELLRDY, b, t + 1);
        }
    } else if (blk < 32) {
        // ================================================= ATTN + FC1 (batch b)
        int b = blk - 16;
        float* sh1 = smem;            // 256
        float* sda = smem + 256;      // 256
        float* ssc = smem + 512;      // 400
        float* red = smem + 912;      // 256
        float* sred = smem + 1280;    // 2048
        float* scov = smem + 3328;    // 400
        float* ctxv = smem + 3728;    // 512
        float* fcout = smem + 4240;   // 512
        for (int i = tid; i < TIN; i += 256) scov[i] = 0.f;
        float covl = 0.f;
        __syncthreads();
        for (int t = 0; t < TT; t++) {
            int p16 = t & 15;
            wait_line<8>(FINRDY, t - 15);
            wait_line<2>(&CELLRDY[b * 16], t + 1);
            if (tid < 64) {
                unsigned long long v = cldu2((const unsigned long long*)(H1B + p16 * 2048 + b * 128) + tid);
                unsigned lo = (unsigned)v, hi = (unsigned)(v >> 32);
                sh1[4 * tid] = bflo(lo); sh1[4 * tid + 1] = bfhi(lo);
                sh1[4 * tid + 2] = bflo(hi); sh1[4 * tid + 3] = bfhi(hi);
            }
            __syncthreads();
            {   // dec_attn
                float a = 0.f;
                const float4* wr = (const float4*)(Wda + (size_t)tid * 256);
                const float4* h4 = (const float4*)sh1;
                for (int k4 = 0; k4 < 64; k4++) {
                    float4 ww = wr[k4], x = h4[k4];
                    a += ww.x * x.x + ww.y * x.y + ww.z * x.z + ww.w * x.w;
                }
                sda[tid] = a;
            }
            __syncthreads();
            int lane = tid & 63, wv = tid >> 6;
            for (int tt = wv; tt < TIN; tt += 4) {
                float cvv = scov[tt];
                const unsigned short* ea = ENCATH + ((size_t)b * TIN + tt) * 256;
                float s4 = 0.f;
#pragma unroll
                for (int j = 0; j < 4; j++) {
                    int c = lane + 64 * j;
                    float x = __uint_as_float((unsigned)ea[c] << 16) + sda[c] + cvv * wcov[c];
                    s4 += vat[c] * fast_tanh(x);
                }
#pragma unroll
                for (int o = 32; o > 0; o >>= 1) s4 += __shfl_xor(s4, o, 64);
                if (lane == 0) ssc[tt] = (ids[b * TIN + tt] == 3) ? -1e30f : s4;
            }
            __syncthreads();
            float m = -1e30f;
            for (int i = tid; i < TIN; i += 256) m = fmaxf(m, ssc[i]);
            red[tid] = m; __syncthreads();
            for (int o = 128; o > 0; o >>= 1) { if (tid < o) red[tid] = fmaxf(red[tid], red[tid + o]); __syncthreads(); }
            m = red[0]; __syncthreads();
            float ps = 0.f;
            for (int i = tid; i < TIN; i += 256) { float ex = __expf(ssc[i] - m); ssc[i] = ex; ps += ex; }
            red[tid] = ps; __syncthreads();
            for (int o = 128; o > 0; o >>= 1) { if (tid < o) red[tid] += red[tid + o]; __syncthreads(); }
            float inv = 1.f / red[0];
            __syncthreads();
            int tgb = tgt[b * TT + t];
            float pc = 0.f, ca = 0.f;
            for (int i = tid; i < TIN; i += 256) {
                float at = ssc[i] * inv; ssc[i] = at;
                float cv = scov[i];
                ca += fminf(at, cv);
                scov[i] = cv + at;
                if (ids[b * TIN + i] == tgb) pc += at;
            }
            red[tid] = pc; __syncthreads();
            for (int o = 128; o > 0; o >>= 1) { if (tid < o) red[tid] += red[tid + o]; __syncthreads(); }
            if (tid == 0) stf(&PCOPYR[p16 * 16 + b], red[0]);
            __syncthreads();
            red[tid] = ca; __syncthreads();
            for (int o = 128; o > 0; o >>= 1) { if (tid < o) red[tid] += red[tid + o]; __syncthreads(); }
            if (tid == 0 && t < tlen[b]) covl += red[0];
            __syncthreads();
            {   // ctx
                float acc[8];
#pragma unroll
                for (int j = 0; j < 8; j++) acc[j] = 0.f;
                for (int i = wv; i < TIN; i += 4) {
                    float a = ssc[i];
                    const unsigned short* es = ENCSH + ((size_t)b * TIN + i) * 512;
#pragma unroll
                    for (int j = 0; j < 8; j++) acc[j] += a * __uint_as_float((unsigned)es[lane + 64 * j] << 16);
                }
#pragma unroll
                for (int j = 0; j < 8; j++) sred[wv * 512 + 64 * j + lane] = acc[j];
                __syncthreads();
                for (int d = tid; d < 512; d += 256)
                    ctxv[d] = sred[d] + sred[512 + d] + sred[1024 + d] + sred[1536 + d];
            }
            __syncthreads();
            if (tid < 256)
                stu(&CTXB[p16 * 4096 + b * 256 + tid], packbf(ctxv[2 * tid], ctxv[2 * tid + 1]));
            // ---- fc1: rows tid and tid+256, K=768=[sh1|ctxv]
#pragma unroll
            for (int half = 0; half < 2; half++) {
                int r = tid + half * 256;
                const uint4* wr = (const uint4*)WV1B + (size_t)r * 96;
                float a = bv1[r];
                for (int i = 0; i < 32; i++) {
                    uint4 q = wr[i]; int k = i * 8;
                    a += bflo(q.x) * sh1[k]     + bfhi(q.x) * sh1[k + 1]
                       + bflo(q.y) * sh1[k + 2] + bfhi(q.y) * sh1[k + 3]
                       + bflo(q.z) * sh1[k + 4] + bfhi(q.z) * sh1[k + 5]
                       + bflo(q.w) * sh1[k + 6] + bfhi(q.w) * sh1[k + 7];
                }
                for (int i = 32; i < 96; i++) {
                    uint4 q = wr[i]; int k = i * 8 - 256;
                    a += bflo(q.x) * ctxv[k]     + bfhi(q.x) * ctxv[k + 1]
                       + bflo(q.y) * ctxv[k + 2] + bfhi(q.y) * ctxv[k + 3]
                       + bflo(q.z) * ctxv[k + 4] + bfhi(q.z) * ctxv[k + 5]
                       + bflo(q.w) * ctxv[k + 6] + bfhi(q.w) * ctxv[k + 7];
                }
                fcout[r] = fmaxf(a, 0.f);
            }
            __syncthreads();
            if (tid < 256)
                stu(&FC1B[(size_t)t * 4096 + b * 256 + tid], packbf(fcout[2 * tid], fcout[2 * tid + 1]));
            if (t == TT - 1 && tid == 0) stf(&COVL[b], covl);
            arrive(ATTNRDY, b, t + 1);
        }
    } else {
        // ================================================= VOCAB (224 blocks; relays; 255 also FINAL)
        int vb = blk - 32;
        int start = (int)(((long long)vb * NV) / NVB);
        int end   = (int)(((long long)(vb + 1) * NV) / NVB);
        float* FC1f = smem + 28672;
        float* scratch = smem + 36864;
        uint4* Wl = (uint4*)smem;
        float nllreg = 0.f;
        // ---- relay election via XCC_ID
        int xcc, isrelay;
        {
            if (tid == 0) {
                int x = 0;
                asm volatile("s_getreg_b32 %0, hwreg(HW_REG_XCC_ID)" : "=s"(x));
                x &= 7;
                int old = atomicCAS(&CLAIM[x * 16], 0, blk + 1);
                scratch[0] = (float)x;
                scratch[1] = (old == 0) ? 1.f : 0.f;
            }
            __syncthreads();
            xcc = (int)scratch[0];
            isrelay = (int)scratch[1];
            __syncthreads();
        }
        for (int i = tid; i < LR * 64; i += 256) {
            int row = i >> 6, k8 = i & 63;
            Wl[k8 * LR + row] = *(const uint4*)(W2b + (size_t)(start + row) * 512 + k8 * 8);
        }
        __syncthreads();

        for (int t = 0; t < TT; t++) {
            int p16 = t & 15;
            wait_line<8>(FINRDY, t - 15);
            if (isrelay) {
                wait_np<2>(ATTNRDY, 16, t + 1, tid);
                const unsigned long long* src = (const unsigned long long*)(FC1B + (size_t)t * 4096);
                unsigned long long* rdst = (unsigned long long*)(RELAY + (size_t)xcc * 409600 + (size_t)t * 4096);
                unsigned long long v[8];
#pragma unroll
                for (int j = 0; j < 8; j++) v[j] = cldu2(src + tid + 256 * j);
#pragma unroll
                for (int j = 0; j < 8; j++) {
                    int m = tid + 256 * j;
                    rdst[m] = v[j];                       // plain cached store (own XCD L2)
                    unsigned lo = (unsigned)v[j], hi = (unsigned)(v[j] >> 32);
                    FC1f[4 * m] = bflo(lo); FC1f[4 * m + 1] = bfhi(lo);
                    FC1f[4 * m + 2] = bflo(hi); FC1f[4 * m + 3] = bfhi(hi);
                }
                arrive(RELAYRDY, xcc, t + 1);             // release: wbl2 flushes relay lines
            } else {
                wait_line<2>(&RELAYRDY[xcc * 16], t + 1);
                const uint4v* Rbase = (const uint4v*)(RELAY + (size_t)xcc * 409600 + (size_t)t * 4096);
                uint4v q0, q1, q2, q3;
                const uint4v* p0 = Rbase + tid;
                const uint4v* p1 = Rbase + tid + 256;
                const uint4v* p2 = Rbase + tid + 512;
                const uint4v* p3 = Rbase + tid + 768;
                asm volatile(
                    "global_load_dwordx4 %0, %4, off sc0\n\t"
                    "global_load_dwordx4 %1, %5, off sc0\n\t"
                    "global_load_dwordx4 %2, %6, off sc0\n\t"
                    "global_load_dwordx4 %3, %7, off sc0\n\t"
                    "s_waitcnt vmcnt(0)"
                    : "=v"(q0), "=v"(q1), "=v"(q2), "=v"(q3)
                    : "v"(p0), "v"(p1), "v"(p2), "v"(p3)
                    : "memory");
#pragma unroll
                for (int j = 0; j < 4; j++) {
                    uint4v q = (j == 0) ? q0 : (j == 1) ? q1 : (j == 2) ? q2 : q3;
                    int i4 = tid + 256 * j;               // uint4 index -> 8 values
#pragma unroll
                    for (int r = 0; r < 4; r++) {
                        unsigned uu = q[r];
                        FC1f[8 * i4 + 2 * r] = bflo(uu);
                        FC1f[8 * i4 + 2 * r + 1] = bfhi(uu);
                    }
                }
                __syncthreads();
            }
            // ---- vocab GEMM + exp partial sums (R12-proven structure)
            int vl = tid & 127, kh = tid >> 7;
            float esum[16];
#pragma unroll
            for (int b = 0; b < 16; b++) esum[b] = 0.f;
            for (int chunk = 0; chunk < 2; chunk++) {
                int v = (chunk == 0) ? (start + vl) : (start + LR + vl);
                bool row_ok = (chunk == 0) ? (vl < LR) : (v < end);
                float acc[16];
#pragma unroll
                for (int b = 0; b < 16; b++) acc[b] = 0.f;
                if (row_ok) {
                    for (int k8l = 0; k8l < 32; k8l++) {
                        int k8 = kh * 32 + k8l;
                        uint4 pw = (chunk == 0) ? Wl[k8 * LR + vl]
                                                : *(const uint4*)(W2b + (size_t)v * 512 + k8 * 8);
                        int k = k8 * 8;
                        float w0 = bflo(pw.x), w1 = bfhi(pw.x);
                        float w2 = bflo(pw.y), w3 = bfhi(pw.y);
                        float w4 = bflo(pw.z), w5 = bfhi(pw.z);
                        float w6 = bflo(pw.w), w7 = bfhi(pw.w);
#pragma unroll
                        for (int b = 0; b < 16; b++) {
                            const float* s = &FC1f[b * 512 + k];
                            acc[b] += w0 * s[0] + w1 * s[1] + w2 * s[2] + w3 * s[3]
                                    + w4 * s[4] + w5 * s[5] + w6 * s[6] + w7 * s[7];
                        }
                    }
                }
                if (kh == 1 && row_ok) {
#pragma unroll
                    for (int b = 0; b < 16; b++) scratch[vl * 17 + b] = acc[b];
                }
                __syncthreads();
                if (kh == 0 && row_ok) {
                    float bias = bv2[v];
#pragma unroll
                    for (int b = 0; b < 16; b++) {
                        float lg = acc[b] + scratch[vl * 17 + b] + bias;
                        if (tgt[b * TT + t] - 2 == v) stf(&LTGTR[p16 * 16 + b], lg);
                        esum[b] += __expf(lg);
                    }
                }
                __syncthreads();
            }
            if (kh == 0) {
#pragma unroll
                for (int b = 0; b < 16; b++) scratch[vl * 17 + b] = esum[b];
            }
            __syncthreads();
            {
                int b = tid >> 4, sl = tid & 15;
                float s = 0.f;
#pragma unroll
                for (int j = 0; j < 8; j++) s += scratch[(sl + 16 * j) * 17 + b];
                FC1f[b * 17 + sl] = s;
            }
            __syncthreads();
            if (tid < 16) {
                float den = 0.f;
#pragma unroll
                for (int j = 0; j < 16; j++) den += FC1f[tid * 17 + j];
                stf(&VPARTR[p16 * 3584 + tid * 224 + vb], den);
            }
            __syncthreads();
            arrive(SVOC, vb, t + 1);

            if (blk == NB - 1) {
                // ---------------- FINAL
                wait_np<2>(SVOC, NVB, t + 1, tid);
                float* fsc = FC1f;
                int lane = tid & 63, wv = tid >> 6;
                for (int bi = 0; bi < 4; bi++) {
                    int b = wv * 4 + bi;
                    float a = 0.f;
                    for (int k = lane; k < 256; k += 64) {
                        unsigned u = cldu(&CTXB[p16 * 4096 + b * 256 + k]);
                        a += bflo(u) * wctx[2 * k] + bfhi(u) * wctx[2 * k + 1];
                    }
                    for (int k = lane; k < 128; k += 64) {
                        unsigned u = cldu(&H1B[p16 * 2048 + b * 128 + k]);
                        a += bflo(u) * wdec[2 * k] + bfhi(u) * wdec[2 * k + 1];
                    }
                    int tok = (t == 0) ? 1 : tgt[b * TT + t - 1];
                    if ((unsigned)tok >= VV) tok = 0;
                    const float* em = emb + (size_t)tok * EMBD;
                    for (int k = lane; k < 128; k += 64) a += em[k] * wemb[k];
#pragma unroll
                    for (int o = 32; o > 0; o >>= 1) a += __shfl_xor(a, o, 64);
                    if (lane == 0) fsc[300 + b] = a;
                }
                {
                    int b = tid >> 4, sl = tid & 15;
                    float s = 0.f;
                    for (int j = sl; j < NVB; j += 16) s += cldf(&VPARTR[p16 * 3584 + b * 224 + j]);
                    fsc[b * 17 + sl] = s;
                }
                __syncthreads();
                if (tid < 16) {
                    int b = tid;
                    float den = 0.f;
#pragma unroll
                    for (int j = 0; j < 16; j++) den += fsc[b * 17 + j];
                    float pg = 1.f / (1.f + __expf(-(fsc[300 + b] + bctx[0])));
                    int tg = tgt[b * TT + t];
                    float pv = (tg >= 2) ? (__expf(cldf(&LTGTR[p16 * 16 + b])) / den) : 0.f;
                    float pr = pg * pv + (1.f - pg) * cldf(&PCOPYR[p16 * 16 + b]);
                    if (t < tlen[b]) nllreg += -logf(pr + 1e-9f);
                }
                if (t == TT - 1) {
                    if (tid < 16) fsc[340 + tid] = nllreg;
                    __syncthreads();
                    if (tid == 0) {
                        float sn = 0.f, sc = 0.f;
                        for (int b = 0; b < 16; b++) { sn += fsc[340 + b]; sc += cldf(&COVL[b]); }
                        out[0] = sn; out[1] = sc; out[2] = sn + sc;
                    }
                }
                arrive(FINRDY, 0, t + 1);
            }
        }
    }
}

// ================================================================ host
extern "C" void kernel_launch(void* const* d_in, const int* in_sizes, int n_in,
                              void* d_out, int out_size, void* d_ws, size_t ws_size,
                              hipStream_t stream) {
    (void)in_sizes; (void)n_in; (void)out_size; (void)ws_size;
    const int*   ids   = (const int*)d_in[0];
    const int*   tgt   = (const int*)d_in[1];
    const int*   tlen  = (const int*)d_in[3];
    const float* emb   = (const float*)d_in[4];
    const float* eWih0 = (const float*)d_in[5];
    const float* eWhh0 = (const float*)d_in[6];
    const float* eb0   = (const float*)d_in[7];
    const float* eWih1 = (const float*)d_in[8];
    const float* eWhh1 = (const float*)d_in[9];
    const float* eb1   = (const float*)d_in[10];
    const float* We2dh = (const float*)d_in[11];
    const float* be2dh = (const float*)d_in[12];
    const float* We2dc = (const float*)d_in[13];
    const float* be2dc = (const float*)d_in[14];
    const float* dWih0 = (const float*)d_in[15];
    const float* dWhh0 = (const float*)d_in[16];
    const float* db0   = (const float*)d_in[17];
    const float* dWih1 = (const float*)d_in[18];
    const float* dWhh1 = (const float*)d_in[19];
    const float* db1   = (const float*)d_in[20];
    const float* Wea   = (const float*)d_in[21];
    const float* bea   = (const float*)d_in[22];
    const float* Wda   = (const float*)d_in[23];
    const float* wcov  = (const float*)d_in[24];
    const float* vat   = (const float*)d_in[25];
    const float* Wv1   = (const float*)d_in[26];
    const float* bv1   = (const float*)d_in[27];
    const float* Wv2   = (const float*)d_in[28];
    const float* bv2   = (const float*)d_in[29];
    const float* wctx  = (const float*)d_in[30];
    const float* bctx  = (const float*)d_in[31];
    const float* wdec  = (const float*)d_in[32];
    const float* wemb  = (const float*)d_in[33];
    float* out = (float*)d_out;

    float* ws = (float*)d_ws;
    float* GX    = ws; ws += (size_t)2 * TIN * B * 1024;   // sub-used after encoder
    float* HSEQ  = ws; ws += (size_t)TIN * B * 512;        // -> RELAY after gx1
    float* ENCS  = ws; ws += (size_t)B * TIN * 512;
    float* ENCATHf = ws; ws += (size_t)B * TIN * 128;
    float* ENCSHf  = ws; ws += (size_t)B * TIN * 256;
    float* HTS   = ws; ws += 2 * B * 512;
    float* CTS   = ws; ws += 2 * B * 512;
    float* H0I   = ws; ws += B * 256;
    float* C0    = ws; ws += B * 256;
    float* H1I   = ws; ws += B * 256;
    float* C1    = ws; ws += B * 256;
    float* H1Bf  = ws; ws += 16 * 2048;                    // u32
    float* CTXBf = ws; ws += 16 * 4096;                    // u32
    float* PCOPYR= ws; ws += 16 * 16;
    float* VPARTR= ws; ws += 16 * 3584;
    float* LTGTR = ws; ws += 16 * 16;
    float* COVL  = ws; ws += 16;
    // ---- zero region ----
    float* ZBASE = ws;
    float* EHBUF = ws; ws += 2 * 2 * B * 256;
    float* ENCSL0f = ws; ws += (size_t)2 * TIN * 16 * 16;
    float* ENCSL1f = ws; ws += (size_t)2 * TIN * 16 * 16;
    float* SLf     = ws; ws += 288 * 16;
    int zcount = (int)(ws - ZBASE);

    int* ENCSL0 = (int*)ENCSL0f;
    int* ENCSL1 = (int*)ENCSL1f;
    int* SLp    = (int*)SLf;
    // GX sub-layout (all dead-after-encoder conversions)
    unsigned short* WV2B = (unsigned short*)GX;                          // 8,191,488 fl
    unsigned short* CW0B = (unsigned short*)(GX + 8191488);              // 196,608 fl
    unsigned short* CW1B = (unsigned short*)(GX + 8388096);              // 262,144 fl
    unsigned short* WV1B = (unsigned short*)(GX + 8650240);              // 196,608 fl
    unsigned*       FC1B = (unsigned*)(GX + 8846848);                    // 409,600 u32
    unsigned*       RELAY = (unsigned*)HSEQ;                             // 3,276,800 u32
    unsigned short* ENCATH = (unsigned short*)ENCATHf;
    unsigned short* ENCSH  = (unsigned short*)ENCSHf;
    unsigned* H1B = (unsigned*)H1Bf;
    unsigned* CTXB = (unsigned*)CTXBf;

    k_zero<<<(zcount + 255) / 256, 256, 0, stream>>>(ZBASE, zcount);
    // ---- encoder (proven persistent unit-split) ----
    k_gx0<<<2 * TIN, 256, 0, stream>>>(ids, emb, eWih0, eb0, GX);
    k_enc_layer<<<32, 256, 0, stream>>>(GX, eWhh0, EHBUF, HSEQ, HTS, CTS, ENCSL0, 0);
    k_gx1<<<2 * TIN, 256, 0, stream>>>(HSEQ, eWih1, eb1, GX);
    k_zero<<<64, 256, 0, stream>>>(EHBUF, 2 * 2 * B * 256);
    k_enc_layer<<<32, 256, 0, stream>>>(GX, eWhh1, EHBUF, ENCS, HTS, CTS, ENCSL1, 1);
    // ---- conversions (GX + HSEQ dead) ----
    k_cvt<<<(NV * 512 + 255) / 256, 256, 0, stream>>>(Wv2, WV2B, NV * 512);
    k_cvt<<<(B * TIN * 512 + 255) / 256, 256, 0, stream>>>(ENCS, ENCSH, B * TIN * 512);
    k_cvt<<<(512 * 768 + 255) / 256, 256, 0, stream>>>(Wv1, WV1B, 512 * 768);
    k_pack<<<(1024 * 384 + 255) / 256, 256, 0, stream>>>(dWih0, 128, dWhh0, 256, CW0B, 1024);
    k_pack<<<(1024 * 512 + 255) / 256, 256, 0, stream>>>(dWih1, 256, dWhh1, 256, CW1B, 1024);
    k_encattn<<<B * TIN / 8, 256, 0, stream>>>(ENCS, Wea, bea, ENCATH);
    k_dec_init<<<32, 256, 0, stream>>>(HTS, CTS, We2dh, be2dh, We2dc, be2dc, H0I, C0, H1I, C1);
    // ---- persistent decoder ----
    k_dec_persist<<<NB, 256, 0, stream>>>(ids, tgt, tlen, emb,
                                          CW0B, db0, CW1B, db1,
                                          Wda, wcov, vat, WV1B, bv1, WV2B, bv2,
                                          wctx, bctx, wdec, wemb,
                                          ENCATH, ENCSH, COVL, H1B, CTXB, FC1B, RELAY,
                                          PCOPYR, VPARTR, LTGTR, H0I, C0, H1I, C1, SLp, out);
}

// Round 14
// 15917.917 us; speedup vs baseline: 1.2690x; 1.2690x over previous
//
#include <hip/hip_runtime.h>
#include <hip/hip_bf16.h>

// Problem constants
#define B    16
#define TIN  400
#define TT   100
#define EMBD 128
#define VV   32000
#define NV   31998
#define NVB  192      // vocab blocks
#define NB   256      // decoder blocks
#define LR   112      // Wv2 rows in LDS per vocab block
// roles: CELL 0-31 | ATTN 32-47 | FC1 48-63 | VOCAB 64-255 (255 also FINAL)
// tokens: UNK=0, START=1, END=2, PAD=3

typedef unsigned uint4v __attribute__((ext_vector_type(4)));

__device__ __forceinline__ float sigf(float x) { return 1.f / (1.f + __expf(-x)); }
__device__ __forceinline__ float fast_tanh(float x) {
    float e = __expf(2.f * x);
    return 1.f - 2.f / (e + 1.f);
}
__device__ __forceinline__ float bflo(unsigned u) { return __uint_as_float(u << 16); }
__device__ __forceinline__ float bfhi(unsigned u) { return __uint_as_float(u & 0xffff0000u); }
__device__ __forceinline__ unsigned short f2bf(float f) {
    unsigned u = __float_as_uint(f);
    return (unsigned short)((u + 0x7fffu + ((u >> 16) & 1u)) >> 16);
}
__device__ __forceinline__ unsigned packbf(float a, float b) {
    return (unsigned)f2bf(a) | ((unsigned)f2bf(b) << 16);
}
// uncached coherence-point ops (flags / tiny scalars only)
__device__ __forceinline__ float cldf(const float* p) {
    return __hip_atomic_load(p, __ATOMIC_RELAXED, __HIP_MEMORY_SCOPE_AGENT);
}
__device__ __forceinline__ unsigned long long cldu2(const unsigned long long* p) {
    return __hip_atomic_load(p, __ATOMIC_RELAXED, __HIP_MEMORY_SCOPE_AGENT);
}
__device__ __forceinline__ void stf(float* p, float v) {
    __hip_atomic_store(p, v, __ATOMIC_RELAXED, __HIP_MEMORY_SCOPE_AGENT);
}

// ---- epoch sync: RELEASE flag (flushes dirty L2 -> MALL); relaxed polling ----
template<int SLP>
__device__ __forceinline__ void wait_np(int* arr, int n, int val, int tid) {
    for (int i = tid; i < n; i += 256) {
        while (__hip_atomic_load(&arr[i * 16], __ATOMIC_RELAXED, __HIP_MEMORY_SCOPE_AGENT) < val)
            __builtin_amdgcn_s_sleep(SLP);
    }
    __syncthreads();
    asm volatile("" ::: "memory");
}
template<int SLP>
__device__ __forceinline__ void wait_line(int* l, int val) {
    if (threadIdx.x == 0) {
        while (__hip_atomic_load(l, __ATOMIC_RELAXED, __HIP_MEMORY_SCOPE_AGENT) < val)
            __builtin_amdgcn_s_sleep(SLP);
    }
    __syncthreads();
    asm volatile("" ::: "memory");
}
__device__ __forceinline__ void arrive(int* arr, int idx, int val) {
    __syncthreads();
    if (threadIdx.x == 0)
        __hip_atomic_store(&arr[idx * 16], val, __ATOMIC_RELEASE, __HIP_MEMORY_SCOPE_AGENT);
}

// ---------------------------------------------------------------- zero
__global__ __launch_bounds__(256) void k_zero(float* __restrict__ p, int n) {
    int i = blockIdx.x * 256 + threadIdx.x;
    if (i < n) p[i] = 0.f;
}

// ---------------------------------------------------------------- fp32 -> bf16 (RNE)
__global__ __launch_bounds__(256) void k_cvt(const float* __restrict__ src, unsigned short* __restrict__ dst, int n) {
    int i = blockIdx.x * 256 + threadIdx.x;
    if (i < n) dst[i] = f2bf(src[i]);
}

// ------------------------------------------------ encoder input GEMM L0 (proven)
__global__ __launch_bounds__(256) void k_gx0(const int* __restrict__ ids, const float* __restrict__ emb,
                                             const float* __restrict__ Wih, const float* __restrict__ bias,
                                             float* __restrict__ gx) {
    int blk = blockIdx.x, dir = blk / TIN, t = blk % TIN;
    __shared__ float se[16][132];
    int tid = threadIdx.x;
    for (int i = tid; i < 16 * 128; i += 256) {
        int b = i >> 7, k = i & 127;
        int id = ids[b * TIN + t];
        if ((unsigned)id >= VV) id = 0;
        se[b][k] = emb[(size_t)id * EMBD + k];
    }
    __syncthreads();
    const float* W = Wih + (size_t)dir * 1024 * EMBD;
    const float* bb = bias + (size_t)dir * 1024;
    float* out = gx + ((size_t)dir * TIN + t) * (B * 1024);
    for (int c = tid; c < 1024; c += 256) {
        float acc[16];
#pragma unroll
        for (int b = 0; b < 16; b++) acc[b] = 0.f;
        const float4* wr = (const float4*)(W + (size_t)c * EMBD);
        for (int k4 = 0; k4 < 32; k4++) {
            float4 w = wr[k4];
            int k = k4 * 4;
#pragma unroll
            for (int b = 0; b < 16; b++)
                acc[b] += w.x * se[b][k] + w.y * se[b][k + 1] + w.z * se[b][k + 2] + w.w * se[b][k + 3];
        }
        float bv = bb[c];
#pragma unroll
        for (int b = 0; b < 16; b++) out[(size_t)b * 1024 + c] = acc[b] + bv;
    }
}

// ------------------------------------------------ encoder input GEMM L1 (proven)
__global__ __launch_bounds__(256) void k_gx1(const float* __restrict__ hseq, const float* __restrict__ Wih,
                                             const float* __restrict__ bias, float* __restrict__ gx) {
    int blk = blockIdx.x, dir = blk / TIN, t = blk % TIN;
    __shared__ float sx[16][516];
    int tid = threadIdx.x;
    for (int i = tid; i < 16 * 512; i += 256) sx[i >> 9][i & 511] = hseq[(size_t)t * B * 512 + i];
    __syncthreads();
    const float* W = Wih + (size_t)dir * 1024 * 512;
    const float* bb = bias + (size_t)dir * 1024;
    float* out = gx + ((size_t)dir * TIN + t) * (B * 1024);
    for (int c = tid; c < 1024; c += 256) {
        float acc[16];
#pragma unroll
        for (int b = 0; b < 16; b++) acc[b] = 0.f;
        const float4* wr = (const float4*)(W + (size_t)c * 512);
        for (int k4 = 0; k4 < 128; k4++) {
            float4 w = wr[k4];
            int k = k4 * 4;
#pragma unroll
            for (int b = 0; b < 16; b++)
                acc[b] += w.x * sx[b][k] + w.y * sx[b][k + 1] + w.z * sx[b][k + 2] + w.w * sx[b][k + 3];
        }
        float bv = bb[c];
#pragma unroll
        for (int b = 0; b < 16; b++) out[(size_t)b * 1024 + c] = acc[b] + bv;
    }
}

// ------------------------------------------------ persistent encoder layer (proven R12)
__device__ __forceinline__ void slot_signal_e(int* sl, int idx) {
    __syncthreads();
    if (threadIdx.x == 0)
        __hip_atomic_store(&sl[idx * 16], 1, __ATOMIC_RELEASE, __HIP_MEMORY_SCOPE_AGENT);
}
__device__ __forceinline__ void slot_wait_e(int* sl, int n, int tid) {
    for (int i = tid; i < n; i += 256) {
        while (__hip_atomic_load(&sl[i * 16], __ATOMIC_RELAXED, __HIP_MEMORY_SCOPE_AGENT) == 0)
            __builtin_amdgcn_s_sleep(2);
    }
    __syncthreads();
    asm volatile("" ::: "memory");
}
__global__ __launch_bounds__(256) void k_enc_layer(const float* __restrict__ gx, const float* __restrict__ Whh,
                                                   float* __restrict__ hbuf, float* __restrict__ hout,
                                                   float* __restrict__ hTs, float* __restrict__ cTs,
                                                   int* __restrict__ slots, int layer) {
    int blk = blockIdx.x;
    int dir = blk >> 4;
    int ublk = blk & 15;
    int tid = threadIdx.x;
    int rp = tid >> 3, q = tid & 7;
    int lr0 = rp * 2, lr1 = lr0 + 1;
    int g0 = lr0 & 3, g1 = lr1 & 3;
    int unit0 = ublk * 16 + (lr0 >> 2);
    int unit1 = ublk * 16 + (lr1 >> 2);
    const float* Wd = Whh + (size_t)dir * 1024 * 256;
    float wreg[64];
    {
        const float* r0 = Wd + (size_t)(g0 * 256 + unit0) * 256 + q * 32;
        const float* r1 = Wd + (size_t)(g1 * 256 + unit1) * 256 + q * 32;
#pragma unroll
        for (int e = 0; e < 32; e++) { wreg[e] = r0[e]; wreg[32 + e] = r1[e]; }
    }
    int ub = tid >> 4, bb = tid & 15;
    float creg = 0.f;
    __shared__ float sh[16 * 288];
    __shared__ float sums[32 * 17];
    __shared__ float sums2[32 * 17];
    int* dirslots = slots + (size_t)dir * TIN * 16 * 16;

    for (int s = 0; s < TIN; s++) {
        int t = dir ? (TIN - 1 - s) : s;
        int par = s & 1;
        {
            const unsigned long long* hp = (const unsigned long long*)(hbuf + ((size_t)par * 2 + dir) * B * 256);
            unsigned long long v[8];
#pragma unroll
            for (int j = 0; j < 8; j++) v[j] = cldu2(hp + tid + 256 * j);
#pragma unroll
            for (int j = 0; j < 8; j++) {
                int k2 = (tid + 256 * j) * 2;
                int b = k2 >> 8, k = k2 & 255;
                float* d = &sh[b * 288 + (k >> 5) * 36 + (k & 31)];
                d[0] = __uint_as_float((unsigned)v[j]);
                d[1] = __uint_as_float((unsigned)(v[j] >> 32));
            }
        }
        __syncthreads();
        float pa0[16], pa1[16];
        for (int b = 0; b < 16; b++) {
            const float4* hv = (const float4*)&sh[b * 288 + q * 36];
            float a0 = 0.f, a1 = 0.f;
#pragma unroll
            for (int j = 0; j < 8; j++) {
                float4 h4 = hv[j];
                a0 += wreg[4 * j] * h4.x + wreg[4 * j + 1] * h4.y + wreg[4 * j + 2] * h4.z + wreg[4 * j + 3] * h4.w;
                a1 += wreg[32 + 4 * j] * h4.x + wreg[33 + 4 * j] * h4.y + wreg[34 + 4 * j] * h4.z + wreg[35 + 4 * j] * h4.w;
            }
            pa0[b] = a0; pa1[b] = a1;
        }
#pragma unroll
        for (int m = 1; m < 8; m <<= 1) {
#pragma unroll
            for (int b = 0; b < 16; b++) {
                pa0[b] += __shfl_xor(pa0[b], m, 64);
                pa1[b] += __shfl_xor(pa1[b], m, 64);
            }
        }
        if (q == 0) {
            float* s0 = (lr0 < 32) ? sums : sums2;
            float* s1 = (lr1 < 32) ? sums : sums2;
            int l0 = lr0 & 31, l1 = lr1 & 31;
#pragma unroll
            for (int b = 0; b < 16; b++) { s0[l0 * 17 + b] = pa0[b]; s1[l1 * 17 + b] = pa1[b]; }
        }
        __syncthreads();
        {
            int unit = ublk * 16 + ub;
            const float* gp = gx + (((size_t)dir * TIN + t) * B + bb) * 1024;
            int lri = ub * 4;
            float ai = ((lri + 0 < 32) ? sums[(lri + 0) * 17 + bb] : sums2[((lri + 0) & 31) * 17 + bb]) + gp[0 * 256 + unit];
            float af = ((lri + 1 < 32) ? sums[(lri + 1) * 17 + bb] : sums2[((lri + 1) & 31) * 17 + bb]) + gp[1 * 256 + unit];
            float ag = ((lri + 2 < 32) ? sums[(lri + 2) * 17 + bb] : sums2[((lri + 2) & 31) * 17 + bb]) + gp[2 * 256 + unit];
            float ao = ((lri + 3 < 32) ? sums[(lri + 3) * 17 + bb] : sums2[((lri + 3) & 31) * 17 + bb]) + gp[3 * 256 + unit];
            float c = sigf(af) * creg + sigf(ai) * fast_tanh(ag);
            float h = sigf(ao) * fast_tanh(c);
            creg = c;
            stf(&hbuf[((size_t)(par ^ 1) * 2 + dir) * B * 256 + (size_t)bb * 256 + unit], h);
            if (layer == 0) hout[((size_t)t * B + bb) * 512 + dir * 256 + unit] = h;
            else            hout[((size_t)bb * TIN + t) * 512 + dir * 256 + unit] = h;
            if (s == TIN - 1) {
                hTs[((size_t)layer * B + bb) * 512 + dir * 256 + unit] = h;
                cTs[((size_t)layer * B + bb) * 512 + dir * 256 + unit] = c;
            }
        }
        int* sl = dirslots + (size_t)s * 16 * 16;
        slot_signal_e(sl, ublk);
        slot_wait_e(sl, 16, tid);
    }
}

// ------------------------------------------------ enc_attn precompute (proven)
__global__ __launch_bounds__(256) void k_encattn(const float* __restrict__ encs, const float* __restrict__ Wea,
                                                 const float* __restrict__ bea, unsigned short* __restrict__ encat) {
    int blk = blockIdx.x;
    __shared__ float sx[8][520];
    int tid = threadIdx.x;
    for (int i = tid; i < 8 * 512; i += 256) {
        int r = i >> 9, k = i & 511;
        sx[r][k] = encs[((size_t)blk * 8 + r) * 512 + k];
    }
    __syncthreads();
    float a[8];
    float bv = bea[tid];
#pragma unroll
    for (int r = 0; r < 8; r++) a[r] = bv;
    const float4* wr = (const float4*)(Wea + (size_t)tid * 512);
    for (int k4 = 0; k4 < 128; k4++) {
        float4 w = wr[k4];
        int k = k4 * 4;
#pragma unroll
        for (int r = 0; r < 8; r++)
            a[r] += w.x * sx[r][k] + w.y * sx[r][k + 1] + w.z * sx[r][k + 2] + w.w * sx[r][k + 3];
    }
#pragma unroll
    for (int r = 0; r < 8; r++)
        encat[((size_t)blk * 8 + r) * 256 + tid] = f2bf(a[r]);
}

// ------------------------------------------------ decoder init (proven)
__global__ __launch_bounds__(256) void k_dec_init(const float* __restrict__ hTs, const float* __restrict__ cTs,
                                                  const float* __restrict__ Wh, const float* __restrict__ bh,
                                                  const float* __restrict__ Wc, const float* __restrict__ bc,
                                                  float* __restrict__ h0s, float* __restrict__ c0,
                                                  float* __restrict__ h1s, float* __restrict__ c1) {
    int idx = blockIdx.x * 256 + threadIdx.x;
    int l = idx >> 12, b = (idx >> 8) & 15, d = idx & 255;
    const float4* h4 = (const float4*)(hTs + ((size_t)l * B + b) * 512);
    const float4* c4 = (const float4*)(cTs + ((size_t)l * B + b) * 512);
    const float4* wh4 = (const float4*)(Wh + (size_t)d * 512);
    const float4* wc4 = (const float4*)(Wc + (size_t)d * 512);
    float ah = bh[d], ac = bc[d];
    for (int k4 = 0; k4 < 128; k4++) {
        float4 w = wh4[k4], x = h4[k4];
        ah += w.x * x.x + w.y * x.y + w.z * x.z + w.w * x.w;
        w = wc4[k4]; x = c4[k4];
        ac += w.x * x.x + w.y * x.y + w.z * x.z + w.w * x.w;
    }
    if (l == 0) { h0s[(size_t)b * 256 + d] = ah; c0[(size_t)b * 256 + d] = ac; }
    else        { h1s[(size_t)b * 256 + d] = ah; c1[(size_t)b * 256 + d] = ac; }
}

// ------------------------------------------------ persistent decoder: immutable per-t dataflow
// H0T/H1T layout: [t*4096 + blk*128 + b*8 + u]   (unit = blk*8+u; block-exclusive 512B)
// CTXT: [t*8192 + b*512 + d] fp32                (b-exclusive 2KB, written by attn block b)
// FC1T: [t*4096 + b*256 + c/2] bf16-pairs        (fc1 block cb owns c in [cb*32,cb*32+32): 64B/b)
// VPT:  [t*3072 + vb*16 + b]                     (vocab block vb owns 64B)
__global__ __launch_bounds__(256, 1) void k_dec_persist(
    const int* __restrict__ ids, const int* __restrict__ tgt, const int* __restrict__ tlen,
    const float* __restrict__ emb,
    const float* __restrict__ dWih0, const float* __restrict__ dWhh0, const float* __restrict__ db0,
    const float* __restrict__ dWih1, const float* __restrict__ dWhh1, const float* __restrict__ db1,
    const float* __restrict__ Wda, const float* __restrict__ wcov, const float* __restrict__ vat,
    const float* __restrict__ Wv1, const float* __restrict__ bv1,
    const unsigned short* __restrict__ W2b, const float* __restrict__ bv2,
    const float* __restrict__ wctx, const float* __restrict__ bctx,
    const float* __restrict__ wdec, const float* __restrict__ wemb,
    const unsigned short* __restrict__ ENCATH, const unsigned short* __restrict__ ENCSH,
    float* __restrict__ COVL,
    float* __restrict__ H0T, float* __restrict__ H1T, float* __restrict__ CTXT,
    unsigned* __restrict__ FC1T, float* __restrict__ VPT,
    float* __restrict__ PCOPY, float* __restrict__ LTGT,
    const float* __restrict__ H0I, const float* __restrict__ C0i,
    const float* __restrict__ H1I, const float* __restrict__ C1i,
    int* __restrict__ FLG, float* __restrict__ out)
{
    __shared__ float smem[39040];
    int blk = blockIdx.x, tid = threadIdx.x;
    int* B1T = FLG;                 // per-t: +t*512 (32 lines)
    int* B2T = FLG + 51200;         // per-t: +t*512
    int* B3T = FLG + 102400;        // per-t: +t*256 (16 lines)
    int* B4T = FLG + 128000;        // per-t: +t*256
    int* SFR = FLG + 153600;        // per-t: +t*128 (8 lines)
    int* SVO = FLG + 166400;        // per-t: +t*3072 (192 lines)

    if (blk < 32) {
        // ================================================= CELL (unit-split, 8 units/block)
        float creg0 = 0.f, creg1 = 0.f;
        if (tid < 128) {
            creg0 = C0i[(size_t)(tid & 15) * 256 + blk * 8 + (tid >> 4)];
            creg1 = C1i[(size_t)(tid & 15) * 256 + blk * 8 + (tid >> 4)];
        }
        for (int t = 0; t < TT; t++) {
            if (t > 0) wait_np<2>(B2T + (t - 1) * 512, 32, 1, tid);
            // stage emb -> [0,2112), h0prev -> [2112,..) swz, h1prev -> [6720,..) swz
            for (int i = tid; i < 2048; i += 256) {
                int b = i >> 7, k = i & 127;
                int tok = (t == 0) ? 1 : tgt[b * TT + t - 1];
                if ((unsigned)tok >= VV) tok = 0;
                smem[b * 132 + k] = emb[(size_t)tok * 128 + k];
            }
#pragma unroll
            for (int j = 0; j < 16; j++) {
                int i = tid + 256 * j;
                int b = i >> 8, k = i & 255;
                float v0, v1;
                if (t == 0) { v0 = H0I[b * 256 + k]; v1 = H1I[b * 256 + k]; }
                else {
                    v0 = H0T[(size_t)(t - 1) * 4096 + (k >> 3) * 128 + b * 8 + (k & 7)];
                    v1 = H1T[(size_t)(t - 1) * 4096 + (k >> 3) * 128 + b * 8 + (k & 7)];
                }
                int off = b * 288 + (k >> 5) * 36 + (k & 31);
                smem[2112 + off] = v0;
                smem[6720 + off] = v1;
            }
            __syncthreads();
            // ---- cell0: 32 gate-rows, K=384
            {
                int r = tid >> 3, q = tid & 7;
                int g = r & 3, u = r >> 2;
                int grow = g * 256 + blk * 8 + u;
                float4 wA[4], wB[8];
                const float4* wi4 = (const float4*)(dWih0 + (size_t)grow * 128 + q * 16);
                const float4* wh4 = (const float4*)(dWhh0 + (size_t)grow * 256 + q * 32);
#pragma unroll
                for (int j = 0; j < 4; j++) wA[j] = wi4[j];
#pragma unroll
                for (int j = 0; j < 8; j++) wB[j] = wh4[j];
                float pa[16];
                for (int b = 0; b < 16; b++) {
                    const float4* xe = (const float4*)&smem[b * 132 + q * 16];
                    const float4* xh = (const float4*)&smem[2112 + b * 288 + q * 36];
                    float a = 0.f;
#pragma unroll
                    for (int j = 0; j < 4; j++) { float4 x = xe[j]; a += wA[j].x * x.x + wA[j].y * x.y + wA[j].z * x.z + wA[j].w * x.w; }
#pragma unroll
                    for (int j = 0; j < 8; j++) { float4 x = xh[j]; a += wB[j].x * x.x + wB[j].y * x.y + wB[j].z * x.z + wB[j].w * x.w; }
                    pa[b] = a;
                }
#pragma unroll
                for (int m = 1; m < 8; m <<= 1)
#pragma unroll
                    for (int b = 0; b < 16; b++) pa[b] += __shfl_xor(pa[b], m, 64);
                if (q == 0)
#pragma unroll
                    for (int b = 0; b < 16; b++) smem[11328 + r * 17 + b] = pa[b];
            }
            __syncthreads();
            if (tid < 128) {
                int u = tid >> 4, b = tid & 15;
                int unit = blk * 8 + u;
                float ai = smem[11328 + (u * 4 + 0) * 17 + b] + db0[unit];
                float af = smem[11328 + (u * 4 + 1) * 17 + b] + db0[256 + unit];
                float ag = smem[11328 + (u * 4 + 2) * 17 + b] + db0[512 + unit];
                float ao = smem[11328 + (u * 4 + 3) * 17 + b] + db0[768 + unit];
                float c = sigf(af) * creg0 + sigf(ai) * fast_tanh(ag);
                float h = sigf(ao) * fast_tanh(c);
                creg0 = c;
                H0T[(size_t)t * 4096 + blk * 128 + b * 8 + u] = h;   // plain cached store
            }
            arrive(B1T + t * 512, blk, 1);
            wait_np<2>(B1T + t * 512, 32, 1, tid);
            // stage full h0(t) -> [2112,..) swz
#pragma unroll
            for (int j = 0; j < 16; j++) {
                int i = tid + 256 * j;
                int b = i >> 8, k = i & 255;
                float v0 = H0T[(size_t)t * 4096 + (k >> 3) * 128 + b * 8 + (k & 7)];
                smem[2112 + b * 288 + (k >> 5) * 36 + (k & 31)] = v0;
            }
            __syncthreads();
            // ---- cell1: 32 gate-rows, K=512 ([h0new | h1prev])
            {
                int r = tid >> 3, q = tid & 7;
                int g = r & 3, u = r >> 2;
                int grow = g * 256 + blk * 8 + u;
                float4 wA[8], wB[8];
                const float4* wi4 = (const float4*)(dWih1 + (size_t)grow * 256 + q * 32);
                const float4* wh4 = (const float4*)(dWhh1 + (size_t)grow * 256 + q * 32);
#pragma unroll
                for (int j = 0; j < 8; j++) { wA[j] = wi4[j]; wB[j] = wh4[j]; }
                float pa[16];
                for (int b = 0; b < 16; b++) {
                    const float4* xa = (const float4*)&smem[2112 + b * 288 + q * 36];
                    const float4* xb = (const float4*)&smem[6720 + b * 288 + q * 36];
                    float a = 0.f;
#pragma unroll
                    for (int j = 0; j < 8; j++) { float4 x = xa[j]; a += wA[j].x * x.x + wA[j].y * x.y + wA[j].z * x.z + wA[j].w * x.w; }
#pragma unroll
                    for (int j = 0; j < 8; j++) { float4 x = xb[j]; a += wB[j].x * x.x + wB[j].y * x.y + wB[j].z * x.z + wB[j].w * x.w; }
                    pa[b] = a;
                }
#pragma unroll
                for (int m = 1; m < 8; m <<= 1)
#pragma unroll
                    for (int b = 0; b < 16; b++) pa[b] += __shfl_xor(pa[b], m, 64);
                if (q == 0)
#pragma unroll
                    for (int b = 0; b < 16; b++) smem[11328 + r * 17 + b] = pa[b];
            }
            __syncthreads();
            if (tid < 128) {
                int u = tid >> 4, b = tid & 15;
                int unit = blk * 8 + u;
                float ai = smem[11328 + (u * 4 + 0) * 17 + b] + db1[unit];
                float af = smem[11328 + (u * 4 + 1) * 17 + b] + db1[256 + unit];
                float ag = smem[11328 + (u * 4 + 2) * 17 + b] + db1[512 + unit];
                float ao = smem[11328 + (u * 4 + 3) * 17 + b] + db1[768 + unit];
                float c = sigf(af) * creg1 + sigf(ai) * fast_tanh(ag);
                float h = sigf(ao) * fast_tanh(c);
                creg1 = c;
                H1T[(size_t)t * 4096 + blk * 128 + b * 8 + u] = h;
            }
            arrive(B2T + t * 512, blk, 1);
        }
    } else if (blk < 48) {
        // ================================================= ATTN (per-batch, coverage in LDS)
        int b = blk - 32;
        float* sh1 = smem; float* sda = smem + 256; float* ssc = smem + 512;
        float* red = smem + 912; float* sred = smem + 1280; float* scov = smem + 3328;
        for (int i = tid; i < TIN; i += 256) scov[i] = 0.f;
        float covl = 0.f;
        __syncthreads();
        for (int t = 0; t < TT; t++) {
            wait_np<2>(B2T + t * 512, 32, 1, tid);
            sh1[tid] = H1T[(size_t)t * 4096 + (tid >> 3) * 128 + b * 8 + (tid & 7)];  // cached
            __syncthreads();
            {
                float a = 0.f;
                const float4* wr = (const float4*)(Wda + (size_t)tid * 256);
                const float4* h4 = (const float4*)sh1;
                for (int k4 = 0; k4 < 64; k4++) {
                    float4 ww = wr[k4], x = h4[k4];
                    a += ww.x * x.x + ww.y * x.y + ww.z * x.z + ww.w * x.w;
                }
                sda[tid] = a;
            }
            __syncthreads();
            int lane = tid & 63, wv = tid >> 6;
            for (int tt = wv; tt < TIN; tt += 4) {
                float cvv = scov[tt];
                const unsigned short* ea = ENCATH + ((size_t)b * TIN + tt) * 256;
                float s4 = 0.f;
#pragma unroll
                for (int j = 0; j < 4; j++) {
                    int c = lane + 64 * j;
                    float x = __uint_as_float((unsigned)ea[c] << 16) + sda[c] + cvv * wcov[c];
                    s4 += vat[c] * fast_tanh(x);
                }
#pragma unroll
                for (int o = 32; o > 0; o >>= 1) s4 += __shfl_xor(s4, o, 64);
                if (lane == 0) ssc[tt] = (ids[b * TIN + tt] == 3) ? -1e30f : s4;
            }
            __syncthreads();
            float m = -1e30f;
            for (int i = tid; i < TIN; i += 256) m = fmaxf(m, ssc[i]);
            red[tid] = m; __syncthreads();
            for (int o = 128; o > 0; o >>= 1) { if (tid < o) red[tid] = fmaxf(red[tid], red[tid + o]); __syncthreads(); }
            m = red[0]; __syncthreads();
            float ps = 0.f;
            for (int i = tid; i < TIN; i += 256) { float ex = __expf(ssc[i] - m); ssc[i] = ex; ps += ex; }
            red[tid] = ps; __syncthreads();
            for (int o = 128; o > 0; o >>= 1) { if (tid < o) red[tid] += red[tid + o]; __syncthreads(); }
            float inv = 1.f / red[0];
            __syncthreads();
            int tgb = tgt[b * TT + t];
            float pc = 0.f, ca = 0.f;
            for (int i = tid; i < TIN; i += 256) {
                float at = ssc[i] * inv; ssc[i] = at;
                float cv = scov[i];
                ca += fminf(at, cv);
                scov[i] = cv + at;
                if (ids[b * TIN + i] == tgb) pc += at;
            }
            red[tid] = pc; __syncthreads();
            for (int o = 128; o > 0; o >>= 1) { if (tid < o) red[tid] += red[tid + o]; __syncthreads(); }
            if (tid == 0) stf(&PCOPY[t * 16 + b], red[0]);
            __syncthreads();
            red[tid] = ca; __syncthreads();
            for (int o = 128; o > 0; o >>= 1) { if (tid < o) red[tid] += red[tid + o]; __syncthreads(); }
            if (tid == 0 && t < tlen[b]) covl += red[0];
            __syncthreads();
            {
                float acc[8];
#pragma unroll
                for (int j = 0; j < 8; j++) acc[j] = 0.f;
                for (int i = wv; i < TIN; i += 4) {
                    float a = ssc[i];
                    const unsigned short* es = ENCSH + ((size_t)b * TIN + i) * 512;
#pragma unroll
                    for (int j = 0; j < 8; j++) acc[j] += a * __uint_as_float((unsigned)es[lane + 64 * j] << 16);
                }
#pragma unroll
                for (int j = 0; j < 8; j++) sred[wv * 512 + 64 * j + lane] = acc[j];
                __syncthreads();
                for (int d = tid; d < 512; d += 256)
                    CTXT[(size_t)t * 8192 + b * 512 + d] =
                        sred[d] + sred[512 + d] + sred[1024 + d] + sred[1536 + d];   // cached
            }
            if (t == TT - 1 && tid == 0) stf(&COVL[b], covl);
            arrive(B3T + t * 256, b, 1);
        }
    } else if (blk < 64) {
        // ================================================= FC1 (32 cols/block, Wv1 slice in LDS)
        int cb = blk - 48;
        float* Wv1s = smem;             // 24576
        float* x = smem + 24576;        // 12352
        float* fcout = smem + 36928;    // 512
        for (int r = 0; r < 32; r++)
            for (int k = tid; k < 768; k += 256)
                Wv1s[r * 768 + k] = Wv1[(size_t)(cb * 32 + r) * 768 + k];
        __syncthreads();
        for (int t = 0; t < TT; t++) {
            wait_np<2>(B3T + t * 256, 16, 1, tid);
            // stage h1 fp32 (scalar, swz-src) + ctx fp32 (float4) into x[b][772]
#pragma unroll
            for (int j = 0; j < 16; j++) {
                int i = tid + 256 * j;
                int b = i >> 8, k = i & 255;
                x[b * 772 + k] = H1T[(size_t)t * 4096 + (k >> 3) * 128 + b * 8 + (k & 7)];
            }
#pragma unroll
            for (int j = 0; j < 8; j++) {
                int i4 = tid + 256 * j;            // 2048 float4s
                int b = i4 >> 7, k = (i4 * 4) & 511;
                *(float4*)&x[b * 772 + 256 + k] = *(const float4*)&CTXT[(size_t)t * 8192 + b * 512 + k];
            }
            __syncthreads();
            {
                int b = tid & 15, cl = tid >> 4;
                const float4* xr = (const float4*)&x[b * 772];
#pragma unroll
                for (int half = 0; half < 2; half++) {
                    int lc = half * 16 + cl;
                    float a = bv1[cb * 32 + lc];
                    const float4* wr = (const float4*)&Wv1s[lc * 768];
                    for (int k4 = 0; k4 < 192; k4++) {
                        float4 ww = wr[k4], xx = xr[k4];
                        a += ww.x * xx.x + ww.y * xx.y + ww.z * xx.z + ww.w * xx.w;
                    }
                    fcout[b * 32 + lc] = fmaxf(a, 0.f);
                }
            }
            __syncthreads();
            {
                int bb = tid >> 4, j = tid & 15;
                FC1T[(size_t)t * 4096 + bb * 256 + cb * 16 + j] =
                    packbf(fcout[bb * 32 + 2 * j], fcout[bb * 32 + 2 * j + 1]);   // cached
            }
            arrive(B4T + t * 256, cb, 1);
            if (blk == 63) {
                wait_np<2>(B4T + t * 256, 16, 1, tid);
                if (tid == 0) {
#pragma unroll
                    for (int rp = 0; rp < 8; rp++)
                        __hip_atomic_store(&SFR[t * 128 + rp * 16], 1, __ATOMIC_RELEASE, __HIP_MEMORY_SCOPE_AGENT);
                }
                __syncthreads();
            }
        }
    } else {
        // ================================================= VOCAB (192 blocks; 255 also FINAL)
        int vb = blk - 64;
        int start = (int)(((long long)vb * NV) / NVB);
        int end   = (int)(((long long)(vb + 1) * NV) / NVB);
        float* FC1f = smem + 28672;
        float* scratch = smem + 36864;
        uint4* Wl = (uint4*)smem;
        float nllreg = 0.f;
        for (int i = tid; i < LR * 64; i += 256) {
            int row = i >> 6, k8 = i & 63;
            Wl[k8 * LR + row] = *(const uint4*)(W2b + (size_t)(start + row) * 512 + k8 * 8);
        }
        __syncthreads();

        for (int t = 0; t < TT; t++) {
            wait_line<2>(&SFR[t * 128 + (vb & 7) * 16], 1);
            {   // stage FC1 (bf16 pairs, plain vector loads - line granular)
                const uint4v* src = (const uint4v*)(FC1T + (size_t)t * 4096);
#pragma unroll
                for (int j = 0; j < 4; j++) {
                    uint4v q = src[tid + 256 * j];
                    int i4 = tid + 256 * j;
#pragma unroll
                    for (int r = 0; r < 4; r++) {
                        unsigned uu = q[r];
                        FC1f[8 * i4 + 2 * r] = bflo(uu);
                        FC1f[8 * i4 + 2 * r + 1] = bfhi(uu);
                    }
                }
            }
            __syncthreads();
            int vl = tid & 127, kh = tid >> 7;
            float esum[16];
#pragma unroll
            for (int b = 0; b < 16; b++) esum[b] = 0.f;
            for (int chunk = 0; chunk < 2; chunk++) {
                int v = (chunk == 0) ? (start + vl) : (start + LR + vl);
                bool row_ok = (chunk == 0) ? (vl < LR) : (v < end);
                float acc[16];
#pragma unroll
                for (int b = 0; b < 16; b++) acc[b] = 0.f;
                if (row_ok) {
                    for (int k8l = 0; k8l < 32; k8l++) {
                        int k8 = kh * 32 + k8l;
                        uint4 pw = (chunk == 0) ? Wl[k8 * LR + vl]
                                                : *(const uint4*)(W2b + (size_t)v * 512 + k8 * 8);
                        int k = k8 * 8;
                        float w0 = bflo(pw.x), w1 = bfhi(pw.x);
                        float w2 = bflo(pw.y), w3 = bfhi(pw.y);
                        float w4 = bflo(pw.z), w5 = bfhi(pw.z);
                        float w6 = bflo(pw.w), w7 = bfhi(pw.w);
#pragma unroll
                        for (int b = 0; b < 16; b++) {
                            const float* s = &FC1f[b * 512 + k];
                            acc[b] += w0 * s[0] + w1 * s[1] + w2 * s[2] + w3 * s[3]
                                    + w4 * s[4] + w5 * s[5] + w6 * s[6] + w7 * s[7];
                        }
                    }
                }
                if (kh == 1 && row_ok) {
#pragma unroll
                    for (int b = 0; b < 16; b++) scratch[vl * 17 + b] = acc[b];
                }
                __syncthreads();
                if (kh == 0 && row_ok) {
                    float bias = bv2[v];
#pragma unroll
                    for (int b = 0; b < 16; b++) {
                        float lg = acc[b] + scratch[vl * 17 + b] + bias;
                        if (tgt[b * TT + t] - 2 == v) stf(&LTGT[t * 16 + b], lg);
                        esum[b] += __expf(lg);
                    }
                }
                __syncthreads();
            }
            if (kh == 0) {
#pragma unroll
                for (int b = 0; b < 16; b++) scratch[vl * 17 + b] = esum[b];
            }
            __syncthreads();
            {
                int b = tid >> 4, sl = tid & 15;
                float s = 0.f;
#pragma unroll
                for (int j = 0; j < 8; j++) s += scratch[(sl + 16 * j) * 17 + b];
                FC1f[b * 17 + sl] = s;
            }
            __syncthreads();
            if (tid < 16) {
                float den = 0.f;
#pragma unroll
                for (int j = 0; j < 16; j++) den += FC1f[tid * 17 + j];
                VPT[(size_t)t * 3072 + vb * 16 + tid] = den;   // cached (block-exclusive line)
            }
            __syncthreads();
            arrive(SVO + t * 3072, vb, 1);

            if (blk == NB - 1) {
                // ---------------- FINAL
                wait_np<2>(SVO + t * 3072, NVB, 1, tid);
                float* fsc = FC1f;
                int lane = tid & 63, wv = tid >> 6;
                for (int bi = 0; bi < 4; bi++) {
                    int b = wv * 4 + bi;
                    float a = 0.f;
                    for (int k = lane; k < 512; k += 64)
                        a += CTXT[(size_t)t * 8192 + b * 512 + k] * wctx[k];
                    for (int k = lane; k < 256; k += 64)
                        a += H1T[(size_t)t * 4096 + (k >> 3) * 128 + b * 8 + (k & 7)] * wdec[k];
                    int tok = (t == 0) ? 1 : tgt[b * TT + t - 1];
                    if ((unsigned)tok >= VV) tok = 0;
                    const float* em = emb + (size_t)tok * EMBD;
                    for (int k = lane; k < 128; k += 64) a += em[k] * wemb[k];
#pragma unroll
                    for (int o = 32; o > 0; o >>= 1) a += __shfl_xor(a, o, 64);
                    if (lane == 0) fsc[300 + b] = a;
                }
                {
                    int b = tid >> 4, sl = tid & 15;
                    float s = 0.f;
                    for (int j = sl; j < NVB; j += 16) s += VPT[(size_t)t * 3072 + j * 16 + b];
                    fsc[b * 17 + sl] = s;
                }
                __syncthreads();
                if (tid < 16) {
                    int b = tid;
                    float den = 0.f;
#pragma unroll
                    for (int j = 0; j < 16; j++) den += fsc[b * 17 + j];
                    float pg = 1.f / (1.f + __expf(-(fsc[300 + b] + bctx[0])));
                    int tg = tgt[b * TT + t];
                    float pv = (tg >= 2) ? (__expf(cldf(&LTGT[t * 16 + b])) / den) : 0.f;
                    float pr = pg * pv + (1.f - pg) * cldf(&PCOPY[t * 16 + b]);
                    if (t < tlen[b]) nllreg += -logf(pr + 1e-9f);
                }
                if (t == TT - 1) {
                    if (tid < 16) fsc[340 + tid] = nllreg;
                    __syncthreads();
                    if (tid == 0) {
                        float sn = 0.f, sc = 0.f;
                        for (int b = 0; b < 16; b++) { sn += fsc[340 + b]; sc += cldf(&COVL[b]); }
                        out[0] = sn; out[1] = sc; out[2] = sn + sc;
                    }
                }
                __syncthreads();
            }
        }
    }
}

// ================================================================ host
extern "C" void kernel_launch(void* const* d_in, const int* in_sizes, int n_in,
                              void* d_out, int out_size, void* d_ws, size_t ws_size,
                              hipStream_t stream) {
    (void)in_sizes; (void)n_in; (void)out_size; (void)ws_size;
    const int*   ids   = (const int*)d_in[0];
    const int*   tgt   = (const int*)d_in[1];
    const int*   tlen  = (const int*)d_in[3];
    const float* emb   = (const float*)d_in[4];
    const float* eWih0 = (const float*)d_in[5];
    const float* eWhh0 = (const float*)d_in[6];
    const float* eb0   = (const float*)d_in[7];
    const float* eWih1 = (const float*)d_in[8];
    const float* eWhh1 = (const float*)d_in[9];
    const float* eb1   = (const float*)d_in[10];
    const float* We2dh = (const float*)d_in[11];
    const float* be2dh = (const float*)d_in[12];
    const float* We2dc = (const float*)d_in[13];
    const float* be2dc = (const float*)d_in[14];
    const float* dWih0 = (const float*)d_in[15];
    const float* dWhh0 = (const float*)d_in[16];
    const float* db0   = (const float*)d_in[17];
    const float* dWih1 = (const float*)d_in[18];
    const float* dWhh1 = (const float*)d_in[19];
    const float* db1   = (const float*)d_in[20];
    const float* Wea   = (const float*)d_in[21];
    const float* bea   = (const float*)d_in[22];
    const float* Wda   = (const float*)d_in[23];
    const float* wcov  = (const float*)d_in[24];
    const float* vat   = (const float*)d_in[25];
    const float* Wv1   = (const float*)d_in[26];
    const float* bv1   = (const float*)d_in[27];
    const float* Wv2   = (const float*)d_in[28];
    const float* bv2   = (const float*)d_in[29];
    const float* wctx  = (const float*)d_in[30];
    const float* bctx  = (const float*)d_in[31];
    const float* wdec  = (const float*)d_in[32];
    const float* wemb  = (const float*)d_in[33];
    float* out = (float*)d_out;

    float* ws = (float*)d_ws;
    float* GX    = ws; ws += (size_t)2 * TIN * B * 1024;   // sub-used after encoder
    float* HSEQ  = ws; ws += (size_t)TIN * B * 512;
    float* ENCS  = ws; ws += (size_t)B * TIN * 512;
    float* ENCATHf = ws; ws += (size_t)B * TIN * 128;      // ushort
    float* ENCSHf  = ws; ws += (size_t)B * TIN * 256;      // ushort
    float* HTS   = ws; ws += 2 * B * 512;
    float* CTS   = ws; ws += 2 * B * 512;
    float* H0I   = ws; ws += B * 256;
    float* C0    = ws; ws += B * 256;
    float* H1I   = ws; ws += B * 256;
    float* C1    = ws; ws += B * 256;
    float* COVL  = ws; ws += B;
    // ---- zero region ----
    float* ZBASE = ws;
    float* EHBUF = ws; ws += 2 * 2 * B * 256;
    float* ENCSL0f = ws; ws += (size_t)2 * TIN * 16 * 16;
    float* ENCSL1f = ws; ws += (size_t)2 * TIN * 16 * 16;
    float* FLGf    = ws; ws += 473600;                     // per-t flag arrays
    int zcount = (int)(ws - ZBASE);

    int* ENCSL0 = (int*)ENCSL0f;
    int* ENCSL1 = (int*)ENCSL1f;
    int* FLG    = (int*)FLGf;
    // GX tail sub-layout (all decoder-phase; GX dead after encoder)
    unsigned short* WV2B = (unsigned short*)GX;            // 8,191,488 floats as ushort pairs
    float* H0T  = GX + 8191488;                            // 409,600
    float* H1T  = GX + 8601088;                            // 409,600
    float* CTXT = GX + 9010688;                            // 819,200
    unsigned* FC1T = (unsigned*)(GX + 9829888);            // 409,600 u32
    float* VPT  = GX + 10239488;                           // 307,200
    float* PCOPY= GX + 10546688;                           // 1,600
    float* LTGT = GX + 10548288;                           // 1,600
    unsigned short* ENCATH = (unsigned short*)ENCATHf;
    unsigned short* ENCSH  = (unsigned short*)ENCSHf;

    k_zero<<<(zcount + 255) / 256, 256, 0, stream>>>(ZBASE, zcount);
    // ---- encoder (proven persistent unit-split) ----
    k_gx0<<<2 * TIN, 256, 0, stream>>>(ids, emb, eWih0, eb0, GX);
    k_enc_layer<<<32, 256, 0, stream>>>(GX, eWhh0, EHBUF, HSEQ, HTS, CTS, ENCSL0, 0);
    k_gx1<<<2 * TIN, 256, 0, stream>>>(HSEQ, eWih1, eb1, GX);
    k_zero<<<64, 256, 0, stream>>>(EHBUF, 2 * 2 * B * 256);
    k_enc_layer<<<32, 256, 0, stream>>>(GX, eWhh1, EHBUF, ENCS, HTS, CTS, ENCSL1, 1);
    // ---- conversions (GX dead after encoder) ----
    k_cvt<<<(NV * 512 + 255) / 256, 256, 0, stream>>>(Wv2, WV2B, NV * 512);
    k_cvt<<<(B * TIN * 512 + 255) / 256, 256, 0, stream>>>(ENCS, ENCSH, B * TIN * 512);
    k_encattn<<<B * TIN / 8, 256, 0, stream>>>(ENCS, Wea, bea, ENCATH);
    k_dec_init<<<32, 256, 0, stream>>>(HTS, CTS, We2dh, be2dh, We2dc, be2dc, H0I, C0, H1I, C1);
    // ---- persistent decoder (immutable per-t dataflow) ----
    k_dec_persist<<<NB, 256, 0, stream>>>(ids, tgt, tlen, emb,
                                          dWih0, dWhh0, db0, dWih1, dWhh1, db1,
                                          Wda, wcov, vat, Wv1, bv1, WV2B, bv2,
                                          wctx, bctx, wdec, wemb,
                                          ENCATH, ENCSH, COVL,
                                          H0T, H1T, CTXT, FC1T, VPT, PCOPY, LTGT,
                                          H0I, C0, H1I, C1, FLG, out);
}